// Round 1
// baseline (227.224 us; speedup 1.0000x reference)
//
#include <hip/hip_runtime.h>

// Rank2SymmetricTensorHead — fused per-node implementation.
// Key insight: gather index == segment index (edge_index[1]), so grouping
// edges by target node lets each block read node_emb[n] once and never
// materialize the (E,C) / (E,C,9) intermediates.

#define SQ3  1.73205080756887729f
#define SQ15 3.87298334620741688f
#define SQ5  2.23606797749978970f

__global__ void count_kernel(const int* __restrict__ idx1, const int* __restrict__ batch,
                             int* __restrict__ cnt, int* __restrict__ bcnt, int E, int N) {
    int i = blockIdx.x * blockDim.x + threadIdx.x;
    if (i < E) atomicAdd(&cnt[idx1[i]], 1);
    if (i < N) atomicAdd(&bcnt[batch[i]], 1);
}

__global__ void scan_kernel(const int* __restrict__ cnt, int* __restrict__ off,
                            int* __restrict__ cursor, int n) {
    __shared__ int part[256];
    int t = threadIdx.x;
    int per = (n + 255) >> 8;
    int base = t * per;
    int s = 0;
    for (int i = 0; i < per; ++i) { int k = base + i; if (k < n) s += cnt[k]; }
    part[t] = s;
    __syncthreads();
    if (t == 0) {
        int run = 0;
        for (int i = 0; i < 256; ++i) { int v = part[i]; part[i] = run; run += v; }
    }
    __syncthreads();
    int run = part[t];
    for (int i = 0; i < per; ++i) {
        int k = base + i;
        if (k < n) { off[k] = run; cursor[k] = run; run += cnt[k]; }
    }
}

__global__ void scatter_kernel(const int* __restrict__ idx1, int* __restrict__ cursor,
                               int* __restrict__ elist, int E) {
    int i = blockIdx.x * blockDim.x + threadIdx.x;
    if (i < E) { int p = atomicAdd(&cursor[idx1[i]], 1); elist[p] = i; }
}

__global__ __launch_bounds__(128)
void node_kernel(const float* __restrict__ emb, const float* __restrict__ vec,
                 const int* __restrict__ cnt, const int* __restrict__ off,
                 const int* __restrict__ elist,
                 const float* __restrict__ sph_w, const float* __restrict__ ln_w,
                 const float* __restrict__ ln_b,
                 const float* __restrict__ W1, const float* __restrict__ b1,
                 const float* __restrict__ W2, const float* __restrict__ b2,
                 const int* __restrict__ batch, float* __restrict__ r2s)
{
    const int n = blockIdx.x;
    const int c = threadIdx.x;           // channel 0..127
    const int lane = c & 63, wid = c >> 6;

    __shared__ float emb_s[9][128];
    __shared__ float no_s[128][9];
    __shared__ float red[2][2];
    __shared__ float red2[2][9];

    #pragma unroll
    for (int l = 0; l < 9; ++l)
        emb_s[l][c] = emb[(size_t)n * 1152 + l * 128 + c];

    const float lw  = ln_w[c];
    const float lb  = ln_b[c];
    const float w0  = sph_w[0], w1 = sph_w[1], w2s = sph_w[2];
    const float sh0 = w0 / sqrtf(1.0f + 1e-6f);   // l0 block after sph_norm
    __syncthreads();

    float acc[9];
    #pragma unroll
    for (int j = 0; j < 9; ++j) acc[j] = 0.f;

    const int cn  = cnt[n];
    const int beg = off[n];

    for (int i = 0; i < cn; ++i) {
        const int e = elist[beg + i];
        const float vx = vec[e * 3 + 0];
        const float vy = vec[e * 3 + 1];
        const float vz = vec[e * 3 + 2];
        const float rr = vx * vx + vy * vy + vz * vz;

        // l1 / l2 spherical harmonics + per-block RMS norm
        const float a1x = SQ3 * vx, a1y = SQ3 * vy, a1z = SQ3 * vz;
        const float c0 = SQ15 * vx * vy;
        const float c1 = SQ15 * vy * vz;
        const float c2 = 0.5f * SQ5 * (3.f * vz * vz - rr);
        const float c3 = SQ15 * vx * vz;
        const float c4 = 0.5f * SQ15 * (vx * vx - vy * vy);
        const float inv1 = w1  / sqrtf((a1x*a1x + a1y*a1y + a1z*a1z) * (1.f/3.f) + 1e-6f);
        const float inv2 = w2s / sqrtf((c0*c0 + c1*c1 + c2*c2 + c3*c3 + c4*c4) * (1.f/5.f) + 1e-6f);
        const float sh1 = a1x * inv1, sh2 = a1y * inv1, sh3 = a1z * inv1;
        const float sh4 = c0 * inv2, sh5 = c1 * inv2, sh6 = c2 * inv2;
        const float sh7 = c3 * inv2, sh8 = c4 * inv2;

        // x_edge[c] = sum_l emb[n,l,c] * sh[l]
        float x = emb_s[0][c] * sh0 + emb_s[1][c] * sh1 + emb_s[2][c] * sh2
                + emb_s[3][c] * sh3 + emb_s[4][c] * sh4 + emb_s[5][c] * sh5
                + emb_s[6][c] * sh6 + emb_s[7][c] * sh7 + emb_s[8][c] * sh8;

        // layernorm over the 128 channels (2 waves)
        float s1 = x, s2 = x * x;
        #pragma unroll
        for (int o = 32; o >= 1; o >>= 1) {
            s1 += __shfl_xor(s1, o);
            s2 += __shfl_xor(s2, o);
        }
        if (lane == 0) { red[wid][0] = s1; red[wid][1] = s2; }
        __syncthreads();
        const float t1 = red[0][0] + red[1][0];
        const float t2 = red[0][1] + red[1][1];
        __syncthreads();
        const float mu  = t1 * (1.f / 128.f);
        const float var = t2 * (1.f / 128.f) - mu * mu;
        const float y = (x - mu) * rsqrtf(var + 1e-5f) * lw + lb;

        // accumulate y * (v outer v)
        acc[0] += y * vx * vx; acc[1] += y * vx * vy; acc[2] += y * vx * vz;
        acc[3] += y * vy * vx; acc[4] += y * vy * vy; acc[5] += y * vy * vz;
        acc[6] += y * vz * vx; acc[7] += y * vz * vy; acc[8] += y * vz * vz;
    }

    // seg_mean over edges
    const float invc = 1.f / (float)(cn > 0 ? cn : 1);
    #pragma unroll
    for (int j = 0; j < 9; ++j) no_s[c][j] = acc[j] * invc;
    __syncthreads();

    // MLP: h[j][k] = silu(sum_c no[c][j]*W1[c][k] + b1[k]); out[j] = sum_k h*W2[k] + b2
    float hh[9];
    #pragma unroll
    for (int j = 0; j < 9; ++j) hh[j] = 0.f;
    for (int cc = 0; cc < 128; ++cc) {
        const float w = W1[cc * 128 + c];   // coalesced; no_s[cc][j] is an LDS broadcast
        #pragma unroll
        for (int j = 0; j < 9; ++j) hh[j] += no_s[cc][j] * w;
    }
    const float b1k = b1[c];
    const float w2k = W2[c];
    float sv[9];
    #pragma unroll
    for (int j = 0; j < 9; ++j) {
        const float hv  = hh[j] + b1k;
        const float sig = 1.f / (1.f + expf(-hv));
        sv[j] = hv * sig * w2k;
    }
    #pragma unroll
    for (int j = 0; j < 9; ++j) {
        #pragma unroll
        for (int o = 32; o >= 1; o >>= 1) sv[j] += __shfl_xor(sv[j], o);
    }
    if (lane == 0) {
        #pragma unroll
        for (int j = 0; j < 9; ++j) red2[wid][j] = sv[j];
    }
    __syncthreads();
    if (c < 9) {
        const float tot = red2[0][c] + red2[1][c] + b2[0];
        atomicAdd(&r2s[batch[n] * 9 + c], tot);
    }
}

__global__ void finalize_kernel(const float* __restrict__ r2s, const int* __restrict__ bcnt,
                                float* __restrict__ out, int M) {
    int i = blockIdx.x * blockDim.x + threadIdx.x;
    if (i < M) {
        int b = i / 9;
        int cb = bcnt[b];
        out[i] = r2s[i] / (float)(cb > 0 ? cb : 1);
    }
}

extern "C" void kernel_launch(void* const* d_in, const int* in_sizes, int n_in,
                              void* d_out, int out_size, void* d_ws, size_t ws_size,
                              hipStream_t stream) {
    const float* emb   = (const float*)d_in[0];
    const float* vec   = (const float*)d_in[1];
    const int*   eidx  = (const int*)  d_in[2];
    const int*   batch = (const int*)  d_in[3];
    const float* sph_w = (const float*)d_in[4];
    const float* ln_w  = (const float*)d_in[5];
    const float* ln_b  = (const float*)d_in[6];
    const float* W1    = (const float*)d_in[7];
    const float* b1    = (const float*)d_in[8];
    const float* W2    = (const float*)d_in[9];
    const float* b2    = (const float*)d_in[10];

    const int N = in_sizes[3];
    const int E = in_sizes[1] / 3;
    const int B = out_size / 9;
    const int* idx1 = eidx + E;   // edge_index[1]

    // workspace layout (ints/floats, 4B each):
    // [cnt N][bcnt B][r2s B*9][off N][cursor N][elist E]  ≈ 0.63 MB
    int*   cnt    = (int*)d_ws;
    int*   bcnt   = cnt + N;
    float* r2s    = (float*)(bcnt + B);
    int*   off    = (int*)(r2s + B * 9);
    int*   cursor = off + N;
    int*   elist  = cursor + N;

    hipMemsetAsync(cnt, 0, (size_t)(N + B + B * 9) * sizeof(int), stream);

    int threads = 256;
    int gridCE = (max(E, N) + threads - 1) / threads;
    count_kernel<<<gridCE, threads, 0, stream>>>(idx1, batch, cnt, bcnt, E, N);
    scan_kernel<<<1, 256, 0, stream>>>(cnt, off, cursor, N);
    scatter_kernel<<<(E + threads - 1) / threads, threads, 0, stream>>>(idx1, cursor, elist, E);
    node_kernel<<<N, 128, 0, stream>>>(emb, vec, cnt, off, elist,
                                       sph_w, ln_w, ln_b, W1, b1, W2, b2,
                                       batch, r2s);
    finalize_kernel<<<(B * 9 + 63) / 64, 64, 0, stream>>>(r2s, bcnt, (float*)d_out, B * 9);
}

// Round 2
// 148.382 us; speedup vs baseline: 1.5313x; 1.5313x over previous
//
#include <hip/hip_runtime.h>

// Rank2SymmetricTensorHead — fused per-node, wave-per-edge implementation.
// gather index == segment index (edge_index[1]) -> group edges by target
// node; each block owns one node, each wave processes edges independently
// (layernorm = in-wave shuffle reduce, no barriers in the edge loop).
// Outer product v⊗v is symmetric: track only 6 unique moments, expand to 9
// at the output write (h[1]==h[3], h[2]==h[6], h[5]==h[7]).

#define SQ3  1.73205080756887729f
#define SQ15 3.87298334620741688f
#define SQ5  2.23606797749978970f

__global__ void count_kernel(const int* __restrict__ idx1, const int* __restrict__ batch,
                             int* __restrict__ cnt, int* __restrict__ bcnt, int E, int N) {
    int i = blockIdx.x * blockDim.x + threadIdx.x;
    if (i < E) atomicAdd(&cnt[idx1[i]], 1);
    if (i < N) atomicAdd(&bcnt[batch[i]], 1);
}

__global__ __launch_bounds__(1024)
void scan_kernel(const int* __restrict__ cnt, int* __restrict__ off,
                 int* __restrict__ cursor, int n) {
    __shared__ int wsum[16];
    const int t = threadIdx.x, lane = t & 63, w = t >> 6;
    const int base = t * 8;
    int v[8];
    int s = 0;
    #pragma unroll
    for (int i = 0; i < 8; ++i) { int k = base + i; v[i] = (k < n) ? cnt[k] : 0; s += v[i]; }
    int incl = s;
    #pragma unroll
    for (int o = 1; o < 64; o <<= 1) { int u = __shfl_up(incl, o); if (lane >= o) incl += u; }
    if (lane == 63) wsum[w] = incl;
    __syncthreads();
    if (t == 0) { int run = 0; for (int i = 0; i < 16; ++i) { int x = wsum[i]; wsum[i] = run; run += x; } }
    __syncthreads();
    int excl = incl - s + wsum[w];
    #pragma unroll
    for (int i = 0; i < 8; ++i) {
        int k = base + i;
        if (k < n) { off[k] = excl; cursor[k] = excl; excl += v[i]; }
    }
}

__global__ void scatter_kernel(const int* __restrict__ idx1, int* __restrict__ cursor,
                               int* __restrict__ elist, int E) {
    int i = blockIdx.x * blockDim.x + threadIdx.x;
    if (i < E) { int p = atomicAdd(&cursor[idx1[i]], 1); elist[p] = i; }
}

__global__ __launch_bounds__(256)
void node_kernel(const float* __restrict__ emb, const float* __restrict__ vec,
                 const int* __restrict__ cnt, const int* __restrict__ off,
                 const int* __restrict__ elist,
                 const float* __restrict__ sph_w, const float* __restrict__ ln_w,
                 const float* __restrict__ ln_b,
                 const float* __restrict__ W1, const float* __restrict__ b1,
                 const float* __restrict__ W2, const float* __restrict__ b2,
                 const int* __restrict__ batch, float* __restrict__ r2s)
{
    const int n    = blockIdx.x;
    const int t    = threadIdx.x;     // 0..255
    const int lane = t & 63;
    const int wv   = t >> 6;          // wave 0..3

    __shared__ float part[4][128][6];   // per-wave moment partials
    __shared__ float no_s[128][6];      // node_outer (6 unique moments)
    __shared__ float mlp2[128][6];      // second-half MLP partials
    __shared__ float red2[2][6];

    // each lane owns channels c0=lane and c1=lane+64; emb in registers
    const int c0 = lane, c1 = lane + 64;
    const float* eb = emb + (size_t)n * 1152;
    float er0[9], er1[9];
    #pragma unroll
    for (int l = 0; l < 9; ++l) { er0[l] = eb[l * 128 + c0]; er1[l] = eb[l * 128 + c1]; }

    const float w1s = sph_w[1], w2s = sph_w[2];
    const float sh0 = sph_w[0] * rsqrtf(1.0f + 1e-6f);
    const float lw0 = ln_w[c0], lb0 = ln_b[c0];
    const float lw1 = ln_w[c1], lb1 = ln_b[c1];

    float acc0[6], acc1[6];
    #pragma unroll
    for (int u = 0; u < 6; ++u) { acc0[u] = 0.f; acc1[u] = 0.f; }

    const int cn = cnt[n], beg = off[n];

    int e = (wv < cn) ? elist[beg + wv] : 0;
    for (int i = wv; i < cn; i += 4) {
        const int nx = i + 4;
        const int e_next = (nx < cn) ? elist[beg + nx] : 0;

        const float vx = vec[e * 3 + 0];
        const float vy = vec[e * 3 + 1];
        const float vz = vec[e * 3 + 2];
        const float rr = vx * vx + vy * vy + vz * vz;

        const float a1x = SQ3 * vx, a1y = SQ3 * vy, a1z = SQ3 * vz;
        const float q0 = SQ15 * vx * vy;
        const float q1 = SQ15 * vy * vz;
        const float q2 = 0.5f * SQ5 * (3.f * vz * vz - rr);
        const float q3 = SQ15 * vx * vz;
        const float q4 = 0.5f * SQ15 * (vx * vx - vy * vy);
        const float inv1 = w1s * rsqrtf((a1x*a1x + a1y*a1y + a1z*a1z) * (1.f/3.f) + 1e-6f);
        const float inv2 = w2s * rsqrtf((q0*q0 + q1*q1 + q2*q2 + q3*q3 + q4*q4) * (1.f/5.f) + 1e-6f);
        const float sh1 = a1x * inv1, sh2 = a1y * inv1, sh3 = a1z * inv1;
        const float sh4 = q0 * inv2, sh5 = q1 * inv2, sh6 = q2 * inv2;
        const float sh7 = q3 * inv2, sh8 = q4 * inv2;

        float x0 = er0[0]*sh0 + er0[1]*sh1 + er0[2]*sh2 + er0[3]*sh3 + er0[4]*sh4
                 + er0[5]*sh5 + er0[6]*sh6 + er0[7]*sh7 + er0[8]*sh8;
        float x1 = er1[0]*sh0 + er1[1]*sh1 + er1[2]*sh2 + er1[3]*sh3 + er1[4]*sh4
                 + er1[5]*sh5 + er1[6]*sh6 + er1[7]*sh7 + er1[8]*sh8;

        // layernorm over 128 channels == full-wave reduce of the 2-channel sums
        float s1 = x0 + x1, s2 = x0 * x0 + x1 * x1;
        #pragma unroll
        for (int o = 32; o >= 1; o >>= 1) {
            s1 += __shfl_xor(s1, o);
            s2 += __shfl_xor(s2, o);
        }
        const float mu  = s1 * (1.f / 128.f);
        const float var = s2 * (1.f / 128.f) - mu * mu;
        const float rinv = rsqrtf(var + 1e-5f);
        const float y0 = (x0 - mu) * rinv * lw0 + lb0;
        const float y1 = (x1 - mu) * rinv * lw1 + lb1;

        // symmetric moments: xx, xy, xz, yy, yz, zz
        {
            const float p = y0 * vx, q = y0 * vy, r = y0 * vz;
            acc0[0] += p * vx; acc0[1] += p * vy; acc0[2] += p * vz;
            acc0[3] += q * vy; acc0[4] += q * vz; acc0[5] += r * vz;
        }
        {
            const float p = y1 * vx, q = y1 * vy, r = y1 * vz;
            acc1[0] += p * vx; acc1[1] += p * vy; acc1[2] += p * vz;
            acc1[3] += q * vy; acc1[4] += q * vz; acc1[5] += r * vz;
        }
        e = e_next;
    }

    #pragma unroll
    for (int u = 0; u < 6; ++u) { part[wv][c0][u] = acc0[u]; part[wv][c1][u] = acc1[u]; }
    __syncthreads();

    // combine wave partials -> no_s, applying seg_mean's 1/cnt
    const float invc = 1.f / (float)(cn > 0 ? cn : 1);
    {
        const int c = t & 127, ub = (t >> 7) * 3;
        #pragma unroll
        for (int u = 0; u < 3; ++u) {
            const int uu = ub + u;
            no_s[c][uu] = (part[0][c][uu] + part[1][c][uu] + part[2][c][uu] + part[3][c][uu]) * invc;
        }
    }
    __syncthreads();

    // MLP: h[u][k] = silu(sum_c no[c][u] * W1[c][k] + b1[k]); inner sum split
    // across thread halves (64 c's each)
    const int k = t & 127, half = t >> 7;
    float hh[6];
    #pragma unroll
    for (int u = 0; u < 6; ++u) hh[u] = 0.f;
    const float* w1p = W1 + (size_t)half * 64 * 128 + k;
    for (int cc = 0; cc < 64; ++cc) {
        const float w = w1p[cc * 128];          // coalesced; L2-resident
        const int c2 = half * 64 + cc;
        #pragma unroll
        for (int u = 0; u < 6; ++u) hh[u] += no_s[c2][u] * w;
    }
    if (half) {
        #pragma unroll
        for (int u = 0; u < 6; ++u) mlp2[k][u] = hh[u];
    }
    __syncthreads();
    if (t < 128) {
        const float b1k = b1[k], w2k = W2[k];
        float sv[6];
        #pragma unroll
        for (int u = 0; u < 6; ++u) {
            const float hv = hh[u] + mlp2[k][u] + b1k;
            const float sg = 1.f / (1.f + expf(-hv));
            sv[u] = hv * sg * w2k;
        }
        #pragma unroll
        for (int u = 0; u < 6; ++u) {
            #pragma unroll
            for (int o = 32; o >= 1; o >>= 1) sv[u] += __shfl_xor(sv[u], o);
        }
        if ((t & 63) == 0) {
            #pragma unroll
            for (int u = 0; u < 6; ++u) red2[t >> 6][u] = sv[u];
        }
    }
    __syncthreads();
    if (t < 9) {
        const int umap[9] = {0, 1, 2, 1, 3, 4, 2, 4, 5};
        const int u = umap[t];
        const float tot = red2[0][u] + red2[1][u] + b2[0];
        atomicAdd(&r2s[batch[n] * 9 + t], tot);
    }
}

__global__ void finalize_kernel(const float* __restrict__ r2s, const int* __restrict__ bcnt,
                                float* __restrict__ out, int M) {
    int i = blockIdx.x * blockDim.x + threadIdx.x;
    if (i < M) {
        int b = i / 9;
        int cb = bcnt[b];
        out[i] = r2s[i] / (float)(cb > 0 ? cb : 1);
    }
}

extern "C" void kernel_launch(void* const* d_in, const int* in_sizes, int n_in,
                              void* d_out, int out_size, void* d_ws, size_t ws_size,
                              hipStream_t stream) {
    const float* emb   = (const float*)d_in[0];
    const float* vec   = (const float*)d_in[1];
    const int*   eidx  = (const int*)  d_in[2];
    const int*   batch = (const int*)  d_in[3];
    const float* sph_w = (const float*)d_in[4];
    const float* ln_w  = (const float*)d_in[5];
    const float* ln_b  = (const float*)d_in[6];
    const float* W1    = (const float*)d_in[7];
    const float* b1    = (const float*)d_in[8];
    const float* W2    = (const float*)d_in[9];
    const float* b2    = (const float*)d_in[10];

    const int N = in_sizes[3];
    const int E = in_sizes[1] / 3;
    const int B = out_size / 9;
    const int* idx1 = eidx + E;   // edge_index[1]

    // ws layout: [cnt N][bcnt B][r2s B*9][off N][cursor N][elist E]
    int*   cnt    = (int*)d_ws;
    int*   bcnt   = cnt + N;
    float* r2s    = (float*)(bcnt + B);
    int*   off    = (int*)(r2s + B * 9);
    int*   cursor = off + N;
    int*   elist  = cursor + N;

    hipMemsetAsync(cnt, 0, (size_t)(N + B + B * 9) * sizeof(int), stream);

    const int threads = 256;
    const int gridCE = (max(E, N) + threads - 1) / threads;
    count_kernel<<<gridCE, threads, 0, stream>>>(idx1, batch, cnt, bcnt, E, N);
    scan_kernel<<<1, 1024, 0, stream>>>(cnt, off, cursor, N);
    scatter_kernel<<<(E + threads - 1) / threads, threads, 0, stream>>>(idx1, cursor, elist, E);
    node_kernel<<<N, 256, 0, stream>>>(emb, vec, cnt, off, elist,
                                       sph_w, ln_w, ln_b, W1, b1, W2, b2,
                                       batch, r2s);
    finalize_kernel<<<(B * 9 + 63) / 64, 64, 0, stream>>>(r2s, bcnt, (float*)d_out, B * 9);
}

// Round 3
// 143.976 us; speedup vs baseline: 1.5782x; 1.0306x over previous
//
#include <hip/hip_runtime.h>

// Rank2SymmetricTensorHead — per-node algebraic-factored implementation.
// layernorm is affine per edge => the edge loop reduces to 66 per-node scalars
// (S1[6][9], S2[6], S3[6]); per-edge mu/var come from per-node m-bar[9] and
// Gram[45] of emb. Edge work is per-thread scalar, no cross-lane ops.

#define SQ3  1.73205080756887729f
#define SQ15 3.87298334620741688f
#define SQ5  2.23606797749978970f

// triangular pair index for (l <= l2), 45 pairs
#define PIDX(l, l2) ((l) * 9 - (l) * ((l) - 1) / 2 + ((l2) - (l)))

__global__ void preproc_kernel(const int* __restrict__ idx1, const int* __restrict__ batch,
                               int* __restrict__ cnt, int* __restrict__ bcnt,
                               int* __restrict__ elist, int slot, int E, int N) {
    int i = blockIdx.x * blockDim.x + threadIdx.x;
    if (i < E) {
        int nn = idx1[i];
        int p = atomicAdd(&cnt[nn], 1);
        if (p < slot) elist[(size_t)nn * slot + p] = i;
    }
    if (i < N) atomicAdd(&bcnt[batch[i]], 1);
}

__device__ const unsigned char d_PL[45] = {
    0,0,0,0,0,0,0,0,0, 1,1,1,1,1,1,1,1, 2,2,2,2,2,2,2, 3,3,3,3,3,3,
    4,4,4,4,4, 5,5,5,5, 6,6,6, 7,7, 8};
__device__ const unsigned char d_PL2[45] = {
    0,1,2,3,4,5,6,7,8, 1,2,3,4,5,6,7,8, 2,3,4,5,6,7,8, 3,4,5,6,7,8,
    4,5,6,7,8, 5,6,7,8, 6,7,8, 7,8, 8};

__global__ __launch_bounds__(256)
void node_kernel(const float* __restrict__ emb, const float* __restrict__ vec,
                 const int* __restrict__ cnt, const int* __restrict__ elist, int slot,
                 const float* __restrict__ sph_w, const float* __restrict__ ln_w,
                 const float* __restrict__ ln_b,
                 const float* __restrict__ W1, const float* __restrict__ b1,
                 const float* __restrict__ W2, const float* __restrict__ b2,
                 const int* __restrict__ batch, float* __restrict__ r2s)
{
    const int n = blockIdx.x;
    const int t = threadIdx.x;          // 0..255

    __shared__ float emb_s[9][133];     // padded: bank(l,c) = (5l + c) % 32
    __shared__ float stats_p[54][2];    // half-channel partials of mbar/Gram
    __shared__ float stats[54];         // [0..8] = mbar raw, [9..53] = Gram raw
    __shared__ float sred[64][68];      // per-edge S contributions (66 used)
    __shared__ float stats2[66];        // reduced S1(54), S2(6), S3(6)
    __shared__ float no_s[128][8];      // node_outer, padded for float4 reads
    __shared__ float mlp2[128][6];
    __shared__ float red2[2][6];

    const int   cntn = cnt[n];
    const int   cnE  = min(cntn, slot);
    const float invc = 1.f / (float)(cntn > 0 ? cntn : 1);
    const float inv128 = 1.f / 128.f;

    // ---- load emb[n] (1152 floats) via float4 ----
    const float* eb = emb + (size_t)n * 1152;
    for (int i4 = t; i4 < 288; i4 += 256) {
        const float4 v4 = *(const float4*)(eb + i4 * 4);
        const int flat = i4 * 4, row = flat >> 7, col = flat & 127;
        emb_s[row][col + 0] = v4.x; emb_s[row][col + 1] = v4.y;
        emb_s[row][col + 2] = v4.z; emb_s[row][col + 3] = v4.w;
    }
    __syncthreads();

    // ---- per-node stats: mbar[9], Gram[45] (raw sums over c) ----
    {
        const int h = t >> 7, item = t & 127;
        if (item < 54) {
            const int cbeg = h * 64;
            float s = 0.f;
            if (item < 9) {
                for (int c = 0; c < 64; ++c) s += emb_s[item][cbeg + c];
            } else {
                const int l = d_PL[item - 9], l2 = d_PL2[item - 9];
                for (int c = 0; c < 64; ++c)
                    s += emb_s[l][cbeg + c] * emb_s[l2][cbeg + c];
            }
            stats_p[item][h] = s;
        }
    }
    __syncthreads();
    if (t < 54) stats[t] = stats_p[t][0] + stats_p[t][1];
    __syncthreads();

    // ---- edge phase: one thread per edge, pure scalar ----
    if (t < cnE) {
        const int e = elist[(size_t)n * slot + t];
        const float vx = vec[e * 3 + 0];
        const float vy = vec[e * 3 + 1];
        const float vz = vec[e * 3 + 2];
        const float rr = vx * vx + vy * vy + vz * vz;

        const float a1x = SQ3 * vx, a1y = SQ3 * vy, a1z = SQ3 * vz;
        const float q0 = SQ15 * vx * vy;
        const float q1 = SQ15 * vy * vz;
        const float q2 = 0.5f * SQ5 * (3.f * vz * vz - rr);
        const float q3 = SQ15 * vx * vz;
        const float q4 = 0.5f * SQ15 * (vx * vx - vy * vy);
        const float inv1 = sph_w[1] * rsqrtf((a1x*a1x + a1y*a1y + a1z*a1z) * (1.f/3.f) + 1e-6f);
        const float inv2 = sph_w[2] * rsqrtf((q0*q0 + q1*q1 + q2*q2 + q3*q3 + q4*q4) * (1.f/5.f) + 1e-6f);

        float sh[9];
        sh[0] = sph_w[0] * rsqrtf(1.0f + 1e-6f);
        sh[1] = a1x * inv1; sh[2] = a1y * inv1; sh[3] = a1z * inv1;
        sh[4] = q0 * inv2;  sh[5] = q1 * inv2;  sh[6] = q2 * inv2;
        sh[7] = q3 * inv2;  sh[8] = q4 * inv2;

        float mu = 0.f;
        #pragma unroll
        for (int l = 0; l < 9; ++l) mu += sh[l] * stats[l];
        mu *= inv128;

        float x2 = 0.f;
        #pragma unroll
        for (int l = 0; l < 9; ++l) {
            x2 += stats[9 + PIDX(l, l)] * sh[l] * sh[l];
            #pragma unroll
            for (int l2 = l + 1; l2 < 9; ++l2)
                x2 += 2.f * stats[9 + PIDX(l, l2)] * sh[l] * sh[l2];
        }
        x2 *= inv128;

        const float var  = x2 - mu * mu;
        const float rinv = rsqrtf(var + 1e-5f);

        float t1[9];
        #pragma unroll
        for (int l = 0; l < 9; ++l) t1[l] = rinv * sh[l];

        const float op[6] = {vx*vx, vx*vy, vx*vz, vy*vy, vy*vz, vz*vz};
        const float mru = rinv * mu;
        #pragma unroll
        for (int u = 0; u < 6; ++u) {
            const float o = op[u];
            #pragma unroll
            for (int l = 0; l < 9; ++l) sred[t][u * 9 + l] = o * t1[l];
            sred[t][54 + u] = o * mru;
            sred[t][60 + u] = o;
        }
    }
    __syncthreads();

    // ---- reduce S over edges ----
    if (t < 66) {
        float s = 0.f;
        for (int e = 0; e < cnE; ++e) s += sred[e][t];
        stats2[t] = s;
    }
    __syncthreads();

    // ---- contraction: no[c][u] = invc*( lw_c*(emb_lc.S1[u] - S2[u]) + lb_c*S3[u] ) ----
    {
        const int c = t & 127, ug = (t >> 7) * 3;
        const float lwc = ln_w[c], lbc = ln_b[c];
        #pragma unroll
        for (int du = 0; du < 3; ++du) {
            const int u = ug + du;
            float a = 0.f;
            #pragma unroll
            for (int l = 0; l < 9; ++l) a += emb_s[l][c] * stats2[u * 9 + l];
            no_s[c][u] = (lwc * (a - stats2[54 + u]) + lbc * stats2[60 + u]) * invc;
        }
    }
    __syncthreads();

    // ---- MLP: h[u][k] = silu(sum_c no[c][u]*W1[c][k] + b1[k]) ----
    const int k = t & 127, h2 = t >> 7;
    float hh[6];
    #pragma unroll
    for (int u = 0; u < 6; ++u) hh[u] = 0.f;
    {
        const float* w1p = W1 + (size_t)(h2 * 64) * 128 + k;
        const int cbase = h2 * 64;
        #pragma unroll 4
        for (int cc = 0; cc < 64; ++cc) {
            const float w = w1p[cc * 128];
            const float4 nv  = *(const float4*)&no_s[cbase + cc][0];
            const float2 nv2 = *(const float2*)&no_s[cbase + cc][4];
            hh[0] += nv.x  * w; hh[1] += nv.y  * w; hh[2] += nv.z * w;
            hh[3] += nv.w  * w; hh[4] += nv2.x * w; hh[5] += nv2.y * w;
        }
    }
    if (h2) {
        #pragma unroll
        for (int u = 0; u < 6; ++u) mlp2[k][u] = hh[u];
    }
    __syncthreads();
    if (t < 128) {
        const float b1k = b1[k], w2k = W2[k];
        float sv[6];
        #pragma unroll
        for (int u = 0; u < 6; ++u) {
            const float hv = hh[u] + mlp2[k][u] + b1k;
            const float sg = 1.f / (1.f + expf(-hv));
            sv[u] = hv * sg * w2k;
        }
        #pragma unroll
        for (int u = 0; u < 6; ++u) {
            #pragma unroll
            for (int o = 32; o >= 1; o >>= 1) sv[u] += __shfl_xor(sv[u], o);
        }
        if ((t & 63) == 0) {
            #pragma unroll
            for (int u = 0; u < 6; ++u) red2[t >> 6][u] = sv[u];
        }
    }
    __syncthreads();
    if (t < 9) {
        const int umap[9] = {0, 1, 2, 1, 3, 4, 2, 4, 5};
        const float tot = red2[0][umap[t]] + red2[1][umap[t]] + b2[0];
        atomicAdd(&r2s[batch[n] * 9 + t], tot);
    }
}

__global__ void finalize_kernel(const float* __restrict__ r2s, const int* __restrict__ bcnt,
                                float* __restrict__ out, int M) {
    int i = blockIdx.x * blockDim.x + threadIdx.x;
    if (i < M) {
        int b = i / 9;
        int cb = bcnt[b];
        out[i] = r2s[i] / (float)(cb > 0 ? cb : 1);
    }
}

extern "C" void kernel_launch(void* const* d_in, const int* in_sizes, int n_in,
                              void* d_out, int out_size, void* d_ws, size_t ws_size,
                              hipStream_t stream) {
    const float* emb   = (const float*)d_in[0];
    const float* vec   = (const float*)d_in[1];
    const int*   eidx  = (const int*)  d_in[2];
    const int*   batch = (const int*)  d_in[3];
    const float* sph_w = (const float*)d_in[4];
    const float* ln_w  = (const float*)d_in[5];
    const float* ln_b  = (const float*)d_in[6];
    const float* W1    = (const float*)d_in[7];
    const float* b1    = (const float*)d_in[8];
    const float* W2    = (const float*)d_in[9];
    const float* b2    = (const float*)d_in[10];

    const int N = in_sizes[3];
    const int E = in_sizes[1] / 3;
    const int B = out_size / 9;
    const int* idx1 = eidx + E;   // edge_index[1]

    // ws layout: [cnt N][bcnt B][r2s B*9][elist N*slot]
    int*   cnt   = (int*)d_ws;
    int*   bcnt  = cnt + N;
    float* r2s   = (float*)(bcnt + B);
    int*   elist = (int*)(r2s + B * 9);

    const size_t fixed = (size_t)(N + B + B * 9) * 4;
    int slot = 64;
    if (ws_size < fixed + (size_t)N * slot * 4) {
        size_t avail = (ws_size > fixed) ? (ws_size - fixed) / ((size_t)N * 4) : 1;
        slot = (int)avail;
        if (slot > 64) slot = 64;
        if (slot < 1)  slot = 1;
    }

    hipMemsetAsync(cnt, 0, fixed, stream);

    const int threads = 256;
    const int gp = (max(E, N) + threads - 1) / threads;
    preproc_kernel<<<gp, threads, 0, stream>>>(idx1, batch, cnt, bcnt, elist, slot, E, N);
    node_kernel<<<N, 256, 0, stream>>>(emb, vec, cnt, elist, slot,
                                       sph_w, ln_w, ln_b, W1, b1, W2, b2,
                                       batch, r2s);
    finalize_kernel<<<(B * 9 + 255) / 256, 256, 0, stream>>>(r2s, bcnt, (float*)d_out, B * 9);
}